// Round 2
// baseline (235.524 us; speedup 1.0000x reference)
//
#include <hip/hip_runtime.h>
#include <math.h>

#define N_POINTS   262144
#define NUM_FREQS  10
#define NUM_VOXELS 512
// W is (1536, 63) row-major; voxel v needs the 189 contiguous floats at W + v*189.

// ---------------------------------------------------------------------------
// Shared posenc + dot body.  w0/w1/w2 are pointers to the 3 rows (63 floats
// each) in ANY address space (global for fallback, LDS for sorted path).
// Double-angle recurrence: 2^f*x is exact in fp32; recurrence error ~1e-4.
// ---------------------------------------------------------------------------
template <typename WPtr>
__device__ __forceinline__ void posenc_dot(float x0, float x1, float x2,
                                           WPtr w0, WPtr w1, WPtr w2,
                                           float& acc0, float& acc1, float& acc2)
{
    acc0 = x0*w0[0] + x1*w0[1] + x2*w0[2];
    acc1 = x0*w1[0] + x1*w1[1] + x2*w1[2];
    acc2 = x0*w2[0] + x1*w2[1] + x2*w2[2];

    float s0, c0, s1, c1, s2, c2;
    sincosf(x0, &s0, &c0);
    sincosf(x1, &s1, &c1);
    sincosf(x2, &s2, &c2);

    #pragma unroll
    for (int f = 0; f < NUM_FREQS; ++f) {
        const int b = 3 + 6*f;   // enc layout per freq: [s0 s1 s2 c0 c1 c2]
        acc0 += s0*w0[b] + s1*w0[b+1] + s2*w0[b+2]
              + c0*w0[b+3] + c1*w0[b+4] + c2*w0[b+5];
        acc1 += s0*w1[b] + s1*w1[b+1] + s2*w1[b+2]
              + c0*w1[b+3] + c1*w1[b+4] + c2*w1[b+5];
        acc2 += s0*w2[b] + s1*w2[b+1] + s2*w2[b+2]
              + c0*w2[b+3] + c1*w2[b+4] + c2*w2[b+5];
        if (f < NUM_FREQS - 1) {
            const float ns0 = 2.0f*s0*c0, nc0 = c0*c0 - s0*s0;
            const float ns1 = 2.0f*s1*c1, nc1 = c1*c1 - s1*s1;
            const float ns2 = 2.0f*s2*c2, nc2 = c2*c2 - s2*s2;
            s0 = ns0; c0 = nc0; s1 = ns1; c1 = nc1; s2 = ns2; c2 = nc2;
        }
    }
}

// ---------------------------------------------------------------------------
// Fallback (round-1 kernel): divergent gather, ~43 us.  Used only if ws_size
// is too small for the sort pipeline.
// ---------------------------------------------------------------------------
__global__ __launch_bounds__(256) void voxlin_fallback(
    const float* __restrict__ X, const float* __restrict__ W,
    const int* __restrict__ row_ids, const int* __restrict__ voxel_ids,
    float* __restrict__ out)
{
    int i = blockIdx.x * 256 + threadIdx.x;
    if (i >= N_POINTS) return;
    const int v = voxel_ids[i];
    const float* __restrict__ w0 = W + v * 189;
    float a0, a1, a2;
    posenc_dot(X[3*i], X[3*i+1], X[3*i+2], w0, w0 + 63, w0 + 126, a0, a1, a2);
    const int r = row_ids[i];
    out[3*r] = a0; out[3*r+1] = a1; out[3*r+2] = a2;
}

// ---------------------------------------------------------------------------
// Pass 2: histogram of voxel ids (counts must be pre-zeroed).
// ---------------------------------------------------------------------------
__global__ __launch_bounds__(256) void p2_hist(
    const int* __restrict__ voxel_ids, int* __restrict__ counts)
{
    int i = blockIdx.x * 256 + threadIdx.x;
    if (i < N_POINTS) atomicAdd(&counts[voxel_ids[i]], 1);
}

// ---------------------------------------------------------------------------
// Pass 3: single-block exclusive scan over 512 counts.
//   counts_cursor[v]  <- exclusive prefix (becomes the scatter cursor)
//   base[v] / base[512] <- segment starts / total
// ---------------------------------------------------------------------------
__global__ __launch_bounds__(NUM_VOXELS) void p3_scan(
    int* __restrict__ counts_cursor, int* __restrict__ base)
{
    __shared__ int tmp[NUM_VOXELS];
    const int t = threadIdx.x;
    const int c = counts_cursor[t];
    tmp[t] = c;
    __syncthreads();
    #pragma unroll
    for (int off = 1; off < NUM_VOXELS; off <<= 1) {
        int add = (t >= off) ? tmp[t - off] : 0;
        __syncthreads();
        tmp[t] += add;
        __syncthreads();
    }
    const int incl = tmp[t];          // inclusive scan
    base[t + 1] = incl;
    if (t == 0) base[0] = 0;
    counts_cursor[t] = incl - c;      // exclusive scan -> cursor start
}

// ---------------------------------------------------------------------------
// Pass 4: scatter points into voxel-sorted order.
//   STAGE=true : store (x0,x1,x2, bitcast(row)) as float4 (coalesced X read,
//                one scattered 16B write).
//   STAGE=false: store only the point index (1 MB ws variant).
// ---------------------------------------------------------------------------
template <bool STAGE>
__global__ __launch_bounds__(256) void p4_scatter(
    const float* __restrict__ X, const int* __restrict__ row_ids,
    const int* __restrict__ voxel_ids, int* __restrict__ cursor,
    float4* __restrict__ f4buf, int* __restrict__ idxbuf)
{
    int i = blockIdx.x * 256 + threadIdx.x;
    if (i >= N_POINTS) return;
    const int v   = voxel_ids[i];
    const int pos = atomicAdd(&cursor[v], 1);   // order within segment is irrelevant
    if (STAGE) {
        float4 val;
        val.x = X[3*i]; val.y = X[3*i+1]; val.z = X[3*i+2];
        val.w = __int_as_float(row_ids[i]);
        f4buf[pos] = val;
    } else {
        idxbuf[pos] = i;
    }
}

// ---------------------------------------------------------------------------
// Pass 5: compute.  2 blocks per voxel (grid = 1024); the W row-triplet is
// wave-uniform -> staged once into 768 B LDS, read as broadcast (conflict-free).
// ---------------------------------------------------------------------------
template <bool STAGE>
__global__ __launch_bounds__(256) void p5_compute(
    const float4* __restrict__ f4buf, const int* __restrict__ idxbuf,
    const float* __restrict__ X, const int* __restrict__ row_ids,
    const float* __restrict__ W, const int* __restrict__ base,
    float* __restrict__ out)
{
    const int v    = blockIdx.x >> 1;
    const int half = blockIdx.x & 1;

    __shared__ float w[3][64];          // 63 floats/row, padded to 64
    const int t = threadIdx.x;
    if (t < 189) w[t / 63][t % 63] = W[v * 189 + t];
    __syncthreads();

    const int s = base[v], e = base[v + 1];
    for (int p = s + half * 256 + t; p < e; p += 512) {
        float x0, x1, x2; int r;
        if (STAGE) {
            const float4 q = f4buf[p];
            x0 = q.x; x1 = q.y; x2 = q.z; r = __float_as_int(q.w);
        } else {
            const int idx = idxbuf[p];
            x0 = X[3*idx]; x1 = X[3*idx+1]; x2 = X[3*idx+2];
            r = row_ids[idx];
        }
        float a0, a1, a2;
        posenc_dot(x0, x1, x2, &w[0][0], &w[1][0], &w[2][0], a0, a1, a2);
        out[3*r] = a0; out[3*r+1] = a1; out[3*r+2] = a2;
    }
}

// ---------------------------------------------------------------------------
extern "C" void kernel_launch(void* const* d_in, const int* in_sizes, int n_in,
                              void* d_out, int out_size, void* d_ws, size_t ws_size,
                              hipStream_t stream) {
    const float* X         = (const float*)d_in[0];
    const float* W         = (const float*)d_in[1];
    const int*   row_ids   = (const int*)d_in[2];
    const int*   voxel_ids = (const int*)d_in[3];
    float*       out       = (float*)d_out;

    const size_t tableBytes = (size_t)(NUM_VOXELS + NUM_VOXELS + 1) * sizeof(int);
    const size_t needStage  = (size_t)N_POINTS * 16 + tableBytes;
    const size_t needIdx    = (size_t)N_POINTS * 4  + tableBytes;

    const int grid256 = (N_POINTS + 255) / 256;   // 1024

    if (ws_size >= needStage || ws_size >= needIdx) {
        const bool stage = (ws_size >= needStage);
        char* ws = (char*)d_ws;
        const size_t bufBytes = stage ? (size_t)N_POINTS * 16 : (size_t)N_POINTS * 4;
        float4* f4buf  = (float4*)ws;                 // ws base alignment >= 16
        int*    idxbuf = (int*)ws;
        int*    counts = (int*)(ws + bufBytes);       // 512 ints (doubles as cursor)
        int*    base   = counts + NUM_VOXELS;         // 513 ints

        hipMemsetAsync(counts, 0, NUM_VOXELS * sizeof(int), stream);
        p2_hist<<<grid256, 256, 0, stream>>>(voxel_ids, counts);
        p3_scan<<<1, NUM_VOXELS, 0, stream>>>(counts, base);
        if (stage) {
            p4_scatter<true ><<<grid256, 256, 0, stream>>>(X, row_ids, voxel_ids, counts, f4buf, idxbuf);
            p5_compute<true ><<<2 * NUM_VOXELS, 256, 0, stream>>>(f4buf, idxbuf, X, row_ids, W, base, out);
        } else {
            p4_scatter<false><<<grid256, 256, 0, stream>>>(X, row_ids, voxel_ids, counts, f4buf, idxbuf);
            p5_compute<false><<<2 * NUM_VOXELS, 256, 0, stream>>>(f4buf, idxbuf, X, row_ids, W, base, out);
        }
    } else {
        voxlin_fallback<<<grid256, 256, 0, stream>>>(X, W, row_ids, voxel_ids, out);
    }
}

// Round 3
// 80.732 us; speedup vs baseline: 2.9174x; 2.9174x over previous
//
#include <hip/hip_runtime.h>
#include <math.h>

#define N_POINTS   262144
#define NUM_FREQS  10
#define NUM_VOXELS 512
// W is (1536, 63) row-major fp32. Voxel v uses rows 3v..3v+2 (189 floats at
// W + v*189, only 4B-aligned). We repack into workspace as bf16:
//   Wp[v] = 3 rows x 64 bf16 (col 63 zero-padded) = 384 B per voxel,
//   base v*384 B -> 16B-aligned, so the gather is 24 global_load_dwordx4
//   per point instead of 189 scalar dword loads (the R1 latency wall).

__device__ __forceinline__ unsigned short f2bf(float f) {
    unsigned int u = __float_as_uint(f);
    unsigned int r = (u + 0x7fffu + ((u >> 16) & 1u)) >> 16;   // RNE
    return (unsigned short)r;
}
__device__ __forceinline__ float bf_lo(unsigned int u) {      // even element
    return __uint_as_float(u << 16);
}
__device__ __forceinline__ float bf_hi(unsigned int u) {      // odd element
    return __uint_as_float(u & 0xffff0000u);
}

// ---------------------------------------------------------------------------
// Pass 1: repack W (fp32, 1536x63) -> Wp (bf16, 512 x 3 x 64). Runs every
// call (inputs are restored and ws re-poisoned before each timed launch).
// ---------------------------------------------------------------------------
__global__ __launch_bounds__(192) void pack_w(
    const float* __restrict__ W, unsigned short* __restrict__ Wp)
{
    const int v = blockIdx.x;
    const int t = threadIdx.x;
    if (t < 189) {
        const int row = t / 63, col = t % 63;
        Wp[v * 192 + row * 64 + col] = f2bf(W[v * 189 + t]);
    } else {
        Wp[v * 192 + (t - 189) * 64 + 63] = 0;   // zero pad col 63
    }
}

// ---------------------------------------------------------------------------
// Pass 2: main. Per point: posenc into enc[64] registers (double-angle
// recurrence: 2^f*x exact in fp32, recurrence err ~1e-4), then dot against
// the voxel's 3 packed rows via 24 aligned 16B loads.
// ---------------------------------------------------------------------------
__global__ __launch_bounds__(256) void voxlin_main(
    const float* __restrict__ X,
    const unsigned short* __restrict__ Wp,
    const int* __restrict__ row_ids,
    const int* __restrict__ voxel_ids,
    float* __restrict__ out)
{
    const int i = blockIdx.x * 256 + threadIdx.x;
    if (i >= N_POINTS) return;

    const float x0 = X[3*i + 0];
    const float x1 = X[3*i + 1];
    const float x2 = X[3*i + 2];
    const int   v  = voxel_ids[i];

    float enc[64];
    enc[0] = x0; enc[1] = x1; enc[2] = x2;
    enc[63] = 0.0f;                      // pairs with the zero pad (avoid NaN*0)

    float s0, c0, s1, c1, s2, c2;
    sincosf(x0, &s0, &c0);
    sincosf(x1, &s1, &c1);
    sincosf(x2, &s2, &c2);
    #pragma unroll
    for (int f = 0; f < NUM_FREQS; ++f) {
        const int b = 3 + 6*f;           // [s0 s1 s2 c0 c1 c2] per freq
        enc[b+0] = s0; enc[b+1] = s1; enc[b+2] = s2;
        enc[b+3] = c0; enc[b+4] = c1; enc[b+5] = c2;
        if (f < NUM_FREQS - 1) {
            const float ns0 = 2.0f*s0*c0, nc0 = c0*c0 - s0*s0;
            const float ns1 = 2.0f*s1*c1, nc1 = c1*c1 - s1*s1;
            const float ns2 = 2.0f*s2*c2, nc2 = c2*c2 - s2*s2;
            s0 = ns0; c0 = nc0; s1 = ns1; c1 = nc1; s2 = ns2; c2 = nc2;
        }
    }

    // Gather: base is 16B-aligned (v*384 bytes). 3 rows x 8 uint4.
    const uint4* __restrict__ wb = (const uint4*)(Wp + (size_t)v * 192);
    float acc[3];
    #pragma unroll
    for (int r = 0; r < 3; ++r) {
        float a = 0.0f;
        #pragma unroll
        for (int k = 0; k < 8; ++k) {
            const uint4 q = wb[r * 8 + k];
            const int e = 8 * k;
            a += bf_lo(q.x) * enc[e+0] + bf_hi(q.x) * enc[e+1]
               + bf_lo(q.y) * enc[e+2] + bf_hi(q.y) * enc[e+3]
               + bf_lo(q.z) * enc[e+4] + bf_hi(q.z) * enc[e+5]
               + bf_lo(q.w) * enc[e+6] + bf_hi(q.w) * enc[e+7];
        }
        acc[r] = a;
    }

    const int rr = row_ids[i];
    out[3*rr + 0] = acc[0];
    out[3*rr + 1] = acc[1];
    out[3*rr + 2] = acc[2];
}

// ---------------------------------------------------------------------------
// Fallback (R1 kernel) if ws is too small for the 192 KB packed table.
// ---------------------------------------------------------------------------
__global__ __launch_bounds__(256) void voxlin_fallback(
    const float* __restrict__ X, const float* __restrict__ W,
    const int* __restrict__ row_ids, const int* __restrict__ voxel_ids,
    float* __restrict__ out)
{
    const int i = blockIdx.x * 256 + threadIdx.x;
    if (i >= N_POINTS) return;
    const float x0 = X[3*i], x1 = X[3*i+1], x2 = X[3*i+2];
    const int v = voxel_ids[i];
    const float* __restrict__ w0 = W + v * 189;
    const float* __restrict__ w1 = w0 + 63;
    const float* __restrict__ w2 = w0 + 126;

    float a0 = x0*w0[0] + x1*w0[1] + x2*w0[2];
    float a1 = x0*w1[0] + x1*w1[1] + x2*w1[2];
    float a2 = x0*w2[0] + x1*w2[1] + x2*w2[2];
    float s0, c0, s1, c1, s2, c2;
    sincosf(x0, &s0, &c0); sincosf(x1, &s1, &c1); sincosf(x2, &s2, &c2);
    #pragma unroll
    for (int f = 0; f < NUM_FREQS; ++f) {
        const int b = 3 + 6*f;
        a0 += s0*w0[b] + s1*w0[b+1] + s2*w0[b+2] + c0*w0[b+3] + c1*w0[b+4] + c2*w0[b+5];
        a1 += s0*w1[b] + s1*w1[b+1] + s2*w1[b+2] + c0*w1[b+3] + c1*w1[b+4] + c2*w1[b+5];
        a2 += s0*w2[b] + s1*w2[b+1] + s2*w2[b+2] + c0*w2[b+3] + c1*w2[b+4] + c2*w2[b+5];
        if (f < NUM_FREQS - 1) {
            const float ns0 = 2.0f*s0*c0, nc0 = c0*c0 - s0*s0;
            const float ns1 = 2.0f*s1*c1, nc1 = c1*c1 - s1*s1;
            const float ns2 = 2.0f*s2*c2, nc2 = c2*c2 - s2*s2;
            s0 = ns0; c0 = nc0; s1 = ns1; c1 = nc1; s2 = ns2; c2 = nc2;
        }
    }
    const int r = row_ids[i];
    out[3*r] = a0; out[3*r+1] = a1; out[3*r+2] = a2;
}

// ---------------------------------------------------------------------------
extern "C" void kernel_launch(void* const* d_in, const int* in_sizes, int n_in,
                              void* d_out, int out_size, void* d_ws, size_t ws_size,
                              hipStream_t stream) {
    const float* X         = (const float*)d_in[0];
    const float* W         = (const float*)d_in[1];
    const int*   row_ids   = (const int*)d_in[2];
    const int*   voxel_ids = (const int*)d_in[3];
    float*       out       = (float*)d_out;

    const int grid256 = (N_POINTS + 255) / 256;   // 1024
    const size_t need = (size_t)NUM_VOXELS * 192 * sizeof(unsigned short); // 192 KB

    if (ws_size >= need) {
        unsigned short* Wp = (unsigned short*)d_ws;
        pack_w<<<NUM_VOXELS, 192, 0, stream>>>(W, Wp);
        voxlin_main<<<grid256, 256, 0, stream>>>(X, Wp, row_ids, voxel_ids, out);
    } else {
        voxlin_fallback<<<grid256, 256, 0, stream>>>(X, W, row_ids, voxel_ids, out);
    }
}

// Round 4
// 76.227 us; speedup vs baseline: 3.0898x; 1.0591x over previous
//
#include <hip/hip_runtime.h>
#include <math.h>

#define N_POINTS   262144
#define NUM_FREQS  10
#define NUM_VOXELS 512
// W is (1536, 63) row-major fp32. Voxel v uses rows 3v..3v+2. We repack into
// ws as bf16: Wp[v] = 3 rows x 64 bf16 (col 63 zero-pad) = 384 B, 16B-aligned
// -> gather is 24 global_load_dwordx4 per point.
// R4: block-local LDS counting sort by voxel (1024-pt window) so a wave's 64
// points share voxels -> ~2x fewer distinct cache-lines per wave gather.

__device__ __forceinline__ unsigned short f2bf(float f) {
    unsigned int u = __float_as_uint(f);
    return (unsigned short)((u + 0x7fffu + ((u >> 16) & 1u)) >> 16);   // RNE
}
__device__ __forceinline__ float bf_lo(unsigned int u) { return __uint_as_float(u << 16); }
__device__ __forceinline__ float bf_hi(unsigned int u) { return __uint_as_float(u & 0xffff0000u); }

// ---------------------------------------------------------------------------
// Pass 1: repack W (fp32 1536x63) -> Wp (bf16 512 x 3 x 64). Runs every call
// (ws is re-poisoned before every timed launch).
// ---------------------------------------------------------------------------
__global__ __launch_bounds__(192) void pack_w(
    const float* __restrict__ W, unsigned short* __restrict__ Wp)
{
    const int v = blockIdx.x;
    const int t = threadIdx.x;
    if (t < 189) {
        const int row = t / 63, col = t % 63;
        Wp[v * 192 + row * 64 + col] = f2bf(W[v * 189 + t]);
    } else {
        Wp[v * 192 + (t - 189) * 64 + 63] = 0;
    }
}

// ---------------------------------------------------------------------------
// posenc into enc[64] (double-angle recurrence; 2^f*x exact in fp32,
// recurrence err ~1e-4) + dot against 3 packed bf16 rows (24 uint4 loads).
// ---------------------------------------------------------------------------
__device__ __forceinline__ void posenc_pack_dot(
    float x0, float x1, float x2, const unsigned short* __restrict__ Wp, int v,
    float& a0, float& a1, float& a2)
{
    float enc[64];
    enc[0] = x0; enc[1] = x1; enc[2] = x2;
    enc[63] = 0.0f;

    float s0, c0, s1, c1, s2, c2;
    sincosf(x0, &s0, &c0);
    sincosf(x1, &s1, &c1);
    sincosf(x2, &s2, &c2);
    #pragma unroll
    for (int f = 0; f < NUM_FREQS; ++f) {
        const int b = 3 + 6*f;           // [s0 s1 s2 c0 c1 c2]
        enc[b+0] = s0; enc[b+1] = s1; enc[b+2] = s2;
        enc[b+3] = c0; enc[b+4] = c1; enc[b+5] = c2;
        if (f < NUM_FREQS - 1) {
            const float ns0 = 2.0f*s0*c0, nc0 = c0*c0 - s0*s0;
            const float ns1 = 2.0f*s1*c1, nc1 = c1*c1 - s1*s1;
            const float ns2 = 2.0f*s2*c2, nc2 = c2*c2 - s2*s2;
            s0 = ns0; c0 = nc0; s1 = ns1; c1 = nc1; s2 = ns2; c2 = nc2;
        }
    }

    const uint4* __restrict__ wb = (const uint4*)(Wp + (size_t)v * 192);
    float acc[3];
    #pragma unroll
    for (int r = 0; r < 3; ++r) {
        float a = 0.0f;
        #pragma unroll
        for (int k = 0; k < 8; ++k) {
            const uint4 q = wb[r * 8 + k];
            const int e = 8 * k;
            a += bf_lo(q.x) * enc[e+0] + bf_hi(q.x) * enc[e+1]
               + bf_lo(q.y) * enc[e+2] + bf_hi(q.y) * enc[e+3]
               + bf_lo(q.z) * enc[e+4] + bf_hi(q.z) * enc[e+5]
               + bf_lo(q.w) * enc[e+6] + bf_hi(q.w) * enc[e+7];
        }
        acc[r] = a;
    }
    a0 = acc[0]; a1 = acc[1]; a2 = acc[2];
}

// ---------------------------------------------------------------------------
// Pass 2: block-local counting sort by voxel, then gather-compute in sorted
// order. Grid = 256 blocks x 1024 threads = exactly N_POINTS.
// ---------------------------------------------------------------------------
__global__ __launch_bounds__(1024, 1) void voxlin_sorted(
    const float* __restrict__ X,
    const unsigned short* __restrict__ Wp,
    const int* __restrict__ row_ids,
    const int* __restrict__ voxel_ids,
    float* __restrict__ out)
{
    __shared__ float4 pts[1024];       // 16 KB  (x,y,z,unused)
    __shared__ int    meta[1024];      // 4 KB   r | (v<<18)
    __shared__ int    hist[NUM_VOXELS];
    __shared__ int    cur[NUM_VOXELS];

    const int t = threadIdx.x;
    const int i = blockIdx.x * 1024 + t;

    const int   v  = voxel_ids[i];
    const float x0 = X[3*i + 0];
    const float x1 = X[3*i + 1];
    const float x2 = X[3*i + 2];
    const int   r  = row_ids[i];

    if (t < NUM_VOXELS) hist[t] = 0;
    __syncthreads();
    atomicAdd(&hist[v], 1);
    __syncthreads();

    // inclusive Hillis-Steele scan over 512 bins (all threads hit barriers)
    const int c = (t < NUM_VOXELS) ? hist[t] : 0;
    #pragma unroll
    for (int off = 1; off < NUM_VOXELS; off <<= 1) {
        int add = (t < NUM_VOXELS && t >= off) ? hist[t - off] : 0;
        __syncthreads();
        if (t < NUM_VOXELS) hist[t] += add;
        __syncthreads();
    }
    if (t < NUM_VOXELS) cur[t] = hist[t] - c;   // exclusive start = cursor
    __syncthreads();

    const int pos = atomicAdd(&cur[v], 1);      // rank within bin (order free)
    pts[pos]  = make_float4(x0, x1, x2, 0.0f);
    meta[pos] = r | (v << 18);                  // r<2^18, v<2^9
    __syncthreads();

    // compute on sorted point t: neighbors share voxels -> shared cache lines
    const float4 q = pts[t];
    const int    m = meta[t];
    const int    sv = m >> 18;
    const int    sr = m & 0x3FFFF;

    float a0, a1, a2;
    posenc_pack_dot(q.x, q.y, q.z, Wp, sv, a0, a1, a2);

    out[3*sr + 0] = a0;
    out[3*sr + 1] = a1;
    out[3*sr + 2] = a2;
}

// ---------------------------------------------------------------------------
// Fallback (R1 kernel) if ws is too small for the 192 KB packed table.
// ---------------------------------------------------------------------------
__global__ __launch_bounds__(256) void voxlin_fallback(
    const float* __restrict__ X, const float* __restrict__ W,
    const int* __restrict__ row_ids, const int* __restrict__ voxel_ids,
    float* __restrict__ out)
{
    const int i = blockIdx.x * 256 + threadIdx.x;
    if (i >= N_POINTS) return;
    const float x0 = X[3*i], x1 = X[3*i+1], x2 = X[3*i+2];
    const int v = voxel_ids[i];
    const float* __restrict__ w0 = W + v * 189;
    const float* __restrict__ w1 = w0 + 63;
    const float* __restrict__ w2 = w0 + 126;

    float a0 = x0*w0[0] + x1*w0[1] + x2*w0[2];
    float a1 = x0*w1[0] + x1*w1[1] + x2*w1[2];
    float a2 = x0*w2[0] + x1*w2[1] + x2*w2[2];
    float s0, c0, s1, c1, s2, c2;
    sincosf(x0, &s0, &c0); sincosf(x1, &s1, &c1); sincosf(x2, &s2, &c2);
    #pragma unroll
    for (int f = 0; f < NUM_FREQS; ++f) {
        const int b = 3 + 6*f;
        a0 += s0*w0[b] + s1*w0[b+1] + s2*w0[b+2] + c0*w0[b+3] + c1*w0[b+4] + c2*w0[b+5];
        a1 += s0*w1[b] + s1*w1[b+1] + s2*w1[b+2] + c0*w1[b+3] + c1*w1[b+4] + c2*w1[b+5];
        a2 += s0*w2[b] + s1*w2[b+1] + s2*w2[b+2] + c0*w2[b+3] + c1*w2[b+4] + c2*w2[b+5];
        if (f < NUM_FREQS - 1) {
            const float ns0 = 2.0f*s0*c0, nc0 = c0*c0 - s0*s0;
            const float ns1 = 2.0f*s1*c1, nc1 = c1*c1 - s1*s1;
            const float ns2 = 2.0f*s2*c2, nc2 = c2*c2 - s2*s2;
            s0 = ns0; c0 = nc0; s1 = ns1; c1 = nc1; s2 = ns2; c2 = nc2;
        }
    }
    const int rr = row_ids[i];
    out[3*rr] = a0; out[3*rr+1] = a1; out[3*rr+2] = a2;
}

// ---------------------------------------------------------------------------
extern "C" void kernel_launch(void* const* d_in, const int* in_sizes, int n_in,
                              void* d_out, int out_size, void* d_ws, size_t ws_size,
                              hipStream_t stream) {
    const float* X         = (const float*)d_in[0];
    const float* W         = (const float*)d_in[1];
    const int*   row_ids   = (const int*)d_in[2];
    const int*   voxel_ids = (const int*)d_in[3];
    float*       out       = (float*)d_out;

    const size_t need = (size_t)NUM_VOXELS * 192 * sizeof(unsigned short); // 192 KB

    if (ws_size >= need) {
        unsigned short* Wp = (unsigned short*)d_ws;
        pack_w<<<NUM_VOXELS, 192, 0, stream>>>(W, Wp);
        voxlin_sorted<<<N_POINTS / 1024, 1024, 0, stream>>>(X, Wp, row_ids, voxel_ids, out);
    } else {
        voxlin_fallback<<<(N_POINTS + 255) / 256, 256, 0, stream>>>(X, W, row_ids, voxel_ids, out);
    }
}